// Round 6
// baseline (164.831 us; speedup 1.0000x reference)
//
#include <hip/hip_runtime.h>

#define BB 8
#define CL 4096
#define QL 512
#define DD 256

typedef unsigned short u16;
typedef float f32x4 __attribute__((ext_vector_type(4)));
typedef short s16x8 __attribute__((ext_vector_type(8)));

static __device__ __forceinline__ u16 f2bf(float x) {
  unsigned int u = __float_as_uint(x);
  u += 0x7FFFu + ((u >> 16) & 1u);
  return (u16)(u >> 16);
}

// ---------------- K0: prep q (bf16 row-major, bf16 transposed, qw dots) ----
// XCD-affine: b = blk & 7 so batch b's qbf/qTbf land in XCD b's L2 (cached!).
__global__ __launch_bounds__(256) void prep_q_k(
    const float* __restrict__ q, const float* __restrict__ w,
    u16* __restrict__ qbf, u16* __restrict__ qTbf, float* __restrict__ qw_g)
{
  __shared__ u16 qs[8][256];
  __shared__ float red[8][32];
  int blk = blockIdx.x;
  int b = blk & 7;
  int j0 = (blk >> 3) * 8;
  int t = threadIdx.x;
  int r = t >> 5;
  int cs = (t & 31) * 8;

  const float* qrow = q + ((size_t)(b * QL + j0 + r)) * DD + cs;
  float4 v0 = *(const float4*)(qrow);
  float4 v1 = *(const float4*)(qrow + 4);
  float4 w0 = *(const float4*)(w + cs);       // w_q
  float4 w1 = *(const float4*)(w + cs + 4);
  float pw = v0.x*w0.x + v0.y*w0.y + v0.z*w0.z + v0.w*w0.w
           + v1.x*w1.x + v1.y*w1.y + v1.z*w1.z + v1.w*w1.w;

  union { u16 u[8]; uint4 v; } pk;
  pk.u[0]=f2bf(v0.x); pk.u[1]=f2bf(v0.y); pk.u[2]=f2bf(v0.z); pk.u[3]=f2bf(v0.w);
  pk.u[4]=f2bf(v1.x); pk.u[5]=f2bf(v1.y); pk.u[6]=f2bf(v1.z); pk.u[7]=f2bf(v1.w);

  *(uint4*)(qbf + ((size_t)(b * QL + j0 + r)) * DD + cs) = pk.v;
  *(uint4*)(&qs[r][cs]) = pk.v;
  red[r][t & 31] = pw;
  __syncthreads();

  if (t < 8) {
    float s = 0.f;
    #pragma unroll
    for (int k = 0; k < 32; ++k) s += red[t][k];
    qw_g[b * QL + j0 + t] = s;
  }

  int d = t;
  union { u16 u[8]; uint4 v; } tp;
  #pragma unroll
  for (int jj = 0; jj < 8; ++jj) tp.u[jj] = qs[jj][d];
  *(uint4*)(qTbf + ((size_t)(b * DD + d)) * QL + j0) = tp.v;
}

// ---------------- K1: 64-row c tile, 8 waves, 2 blocks/CU -----------------
// nt stores for out/part (no cache pollution); nt load for streaming c.
// L2 per XCD then holds exactly qbf+qTbf (4 MB) for the GEMM B-streams.
__global__ __launch_bounds__(512, 4) void attn_main_k(
    const float* __restrict__ c, const float* __restrict__ w,
    const u16* __restrict__ qbf, const u16* __restrict__ qTbf,
    const float* __restrict__ qw_g,
    float* __restrict__ pm_g, float* __restrict__ z_g,
    float* __restrict__ part_g, float* __restrict__ out)
{
  __shared__ u16 pool[64 * 512];     // cm: [r*256+(d^swz)] (32KB); P: [r*512+(j^swz)] (64KB)
  __shared__ float qw_s[QL];
  __shared__ float cw_s[64];
  __shared__ float red_m[64][8];     // [row][wave]
  __shared__ float red_z[64][8];
  __shared__ float invz_s[64];
  __shared__ float wgt_s[64];

  int t = threadIdx.x;
  int blk = blockIdx.x;
  int b = blk & 7;
  int tile = blk >> 3;
  int it0 = tile * 64;

  // ---- staging: c tile -> cm bf16 LDS (swizzled), cw dots, seg0 copy ----
  {
    int r = t >> 3;
    int cg = (t & 7) * 32;
    int swz = (r & 7) << 3;
    const float* crow = c + ((size_t)(b * CL + it0 + r)) * DD + cg;
    float* outrow = out + ((size_t)(b * CL + it0 + r)) * (4 * DD) + cg;
    float pcw = 0.f;
    #pragma unroll
    for (int u = 0; u < 32; u += 4) {
      f32x4 cv  = __builtin_nontemporal_load((const f32x4*)(crow + u));
      f32x4 wcv = *(const f32x4*)(w + DD + cg + u);      // w_c
      f32x4 wmv = *(const f32x4*)(w + 2 * DD + cg + u);  // w_m
      __builtin_nontemporal_store(cv, (f32x4*)(outrow + u));  // segment 0
      pcw += cv[0]*wcv[0] + cv[1]*wcv[1] + cv[2]*wcv[2] + cv[3]*wcv[3];
      ushort4 hv;
      hv.x = f2bf(cv[0] * wmv[0]); hv.y = f2bf(cv[1] * wmv[1]);
      hv.z = f2bf(cv[2] * wmv[2]); hv.w = f2bf(cv[3] * wmv[3]);
      *(ushort4*)(&pool[r * 256 + ((cg + u) ^ swz)]) = hv;
    }
    pcw += __shfl_xor(pcw, 1);
    pcw += __shfl_xor(pcw, 2);
    pcw += __shfl_xor(pcw, 4);
    if ((t & 7) == 0) cw_s[r] = pcw;
    qw_s[t] = qw_g[b * QL + t];
  }
  __syncthreads();

  int wv = t >> 6;       // wave 0..7
  int ln = t & 63;
  int lr = ln & 15;
  int lg = ln >> 4;
  int jc = wv * 64;      // GEMM1 j-chunk
  int aswz = (lr & 7) << 3;

  // ---- GEMM1: S chunk = cm(64x256) @ q^T; B frags from L2, k+1 prefetch --
  f32x4 acc[4][4];
  #pragma unroll
  for (int m = 0; m < 4; ++m)
    #pragma unroll
    for (int n = 0; n < 4; ++n) acc[m][n] = (f32x4){0.f, 0.f, 0.f, 0.f};

  const u16* qb = qbf + (size_t)b * QL * DD + (size_t)(jc + lr) * DD + lg * 8;
  s16x8 bqn[4];
  #pragma unroll
  for (int n = 0; n < 4; ++n) bqn[n] = *(const s16x8*)(qb + (size_t)(n * 16) * DD);
  #pragma unroll
  for (int kk = 0; kk < 8; ++kk) {
    s16x8 bqc[4];
    #pragma unroll
    for (int n = 0; n < 4; ++n) bqc[n] = bqn[n];
    if (kk < 7) {
      #pragma unroll
      for (int n = 0; n < 4; ++n)
        bqn[n] = *(const s16x8*)(qb + (size_t)(n * 16) * DD + (kk + 1) * 32);
    }
    s16x8 a[4];
    #pragma unroll
    for (int m = 0; m < 4; ++m)
      a[m] = *(const s16x8*)(&pool[(m * 16 + lr) * 256 + ((kk * 32 + lg * 8) ^ aswz)]);
    #pragma unroll
    for (int m = 0; m < 4; ++m)
      #pragma unroll
      for (int n = 0; n < 4; ++n)
        acc[m][n] = __builtin_amdgcn_mfma_f32_16x16x32_bf16(a[m], bqc[n], acc[m][n], 0, 0, 0);
  }

  // ---- softmax pass 1: bias + row max (D: col=lr->j, row=lg*4+rr->i) ----
  float qwv[4];
  #pragma unroll
  for (int n = 0; n < 4; ++n) qwv[n] = qw_s[jc + n * 16 + lr];

  #pragma unroll
  for (int m = 0; m < 4; ++m) {
    #pragma unroll
    for (int rr = 0; rr < 4; ++rr) {
      int row = m * 16 + lg * 4 + rr;
      float cwv = cw_s[row];
      float mx = -1e30f;
      #pragma unroll
      for (int n = 0; n < 4; ++n) {
        float s = acc[m][n][rr] + cwv + qwv[n];
        acc[m][n][rr] = s;
        mx = fmaxf(mx, s);
      }
      mx = fmaxf(mx, __shfl_xor(mx, 1));
      mx = fmaxf(mx, __shfl_xor(mx, 2));
      mx = fmaxf(mx, __shfl_xor(mx, 4));
      mx = fmaxf(mx, __shfl_xor(mx, 8));
      if (lr == 0) red_m[row][wv] = mx;
    }
  }
  __syncthreads();   // red_m visible; cm reads done -> pool reusable as P

  // ---- softmax pass 2: exp, write raw-exp P (swizzled), z partials ----
  #pragma unroll
  for (int m = 0; m < 4; ++m) {
    #pragma unroll
    for (int rr = 0; rr < 4; ++rr) {
      int row = m * 16 + lg * 4 + rr;
      float4 m0 = *(const float4*)(&red_m[row][0]);
      float4 m1 = *(const float4*)(&red_m[row][4]);
      float mr = fmaxf(fmaxf(fmaxf(m0.x, m0.y), fmaxf(m0.z, m0.w)),
                       fmaxf(fmaxf(m1.x, m1.y), fmaxf(m1.z, m1.w)));
      int pswz = (row & 7) << 3;
      float s = 0.f;
      #pragma unroll
      for (int n = 0; n < 4; ++n) {
        float e = __expf(acc[m][n][rr] - mr);
        pool[row * 512 + ((jc + n * 16 + lr) ^ pswz)] = f2bf(e);
        s += e;
      }
      s += __shfl_xor(s, 1);
      s += __shfl_xor(s, 2);
      s += __shfl_xor(s, 4);
      s += __shfl_xor(s, 8);
      if (lr == 0) red_z[row][wv] = s;
    }
  }
  __syncthreads();   // P + red_z visible

  // ---- wave 0: per-row invz/wgt into LDS; pm/z stats to global ----
  if (wv == 0) {
    int row = ln;  // 64 lanes -> 64 rows
    float4 m0 = *(const float4*)(&red_m[row][0]);
    float4 m1 = *(const float4*)(&red_m[row][4]);
    float mr = fmaxf(fmaxf(fmaxf(m0.x, m0.y), fmaxf(m0.z, m0.w)),
                     fmaxf(fmaxf(m1.x, m1.y), fmaxf(m1.z, m1.w)));
    float4 z0 = *(const float4*)(&red_z[row][0]);
    float4 z1 = *(const float4*)(&red_z[row][4]);
    float z = z0.x + z0.y + z0.z + z0.w + z1.x + z1.y + z1.z + z1.w;
    invz_s[row] = 1.0f / z;
    float pmx = mr;
    #pragma unroll
    for (int o = 1; o < 64; o <<= 1) pmx = fmaxf(pmx, __shfl_xor(pmx, o));
    float wg = __expf(mr - pmx);
    wgt_s[row] = wg;
    float zs = wg;
    #pragma unroll
    for (int o = 1; o < 64; o <<= 1) zs += __shfl_xor(zs, o);
    if (ln == 0) { pm_g[b * 64 + tile] = pmx; z_g[b * 64 + tile] = zs; }
  }

  // ---- GEMM2: c2q = P(64x512) @ q(512x256); waves split d in 32s ----
  f32x4 o2[4][2];
  #pragma unroll
  for (int m = 0; m < 4; ++m)
    #pragma unroll
    for (int n = 0; n < 2; ++n) o2[m][n] = (f32x4){0.f, 0.f, 0.f, 0.f};

  int dc = wv * 32;
  const u16* qtb = qTbf + (size_t)b * DD * QL + (size_t)(dc + lr) * QL + lg * 8;
  s16x8 bvn[2];
  #pragma unroll
  for (int n = 0; n < 2; ++n) bvn[n] = *(const s16x8*)(qtb + (size_t)(n * 16) * QL);
  #pragma unroll 4
  for (int kk = 0; kk < 16; ++kk) {
    s16x8 bvc[2];
    #pragma unroll
    for (int n = 0; n < 2; ++n) bvc[n] = bvn[n];
    if (kk < 15) {
      #pragma unroll
      for (int n = 0; n < 2; ++n)
        bvn[n] = *(const s16x8*)(qtb + (size_t)(n * 16) * QL + (kk + 1) * 32);
    }
    s16x8 pa[4];
    #pragma unroll
    for (int m = 0; m < 4; ++m)
      pa[m] = *(const s16x8*)(&pool[(m * 16 + lr) * 512 + ((kk * 32 + lg * 8) ^ aswz)]);
    #pragma unroll
    for (int m = 0; m < 4; ++m)
      #pragma unroll
      for (int n = 0; n < 2; ++n)
        o2[m][n] = __builtin_amdgcn_mfma_f32_16x16x32_bf16(pa[m], bvc[n], o2[m][n], 0, 0, 0);
  }
  __syncthreads();   // invz_s/wgt_s visible

  // ---- epilogue: segments 1 (c2q), 2 (c*c2q), q2c partial (all nt) ----
  #pragma unroll
  for (int n = 0; n < 2; ++n) {
    int dcol = dc + n * 16 + lr;
    float psum = 0.f;
    #pragma unroll
    for (int m = 0; m < 4; ++m)
      #pragma unroll
      for (int rr = 0; rr < 4; ++rr) {
        int row = m * 16 + lg * 4 + rr;
        int grow = it0 + row;
        float c2q = o2[m][n][rr] * invz_s[row];
        float cv = c[((size_t)(b * CL + grow)) * DD + dcol];
        size_t ob = ((size_t)(b * CL + grow)) * (4 * DD);
        __builtin_nontemporal_store(c2q, out + ob + DD + dcol);
        __builtin_nontemporal_store(cv * c2q, out + ob + 2 * DD + dcol);
        psum += wgt_s[row] * cv;
      }
    psum += __shfl_xor(psum, 16);
    psum += __shfl_xor(psum, 32);
    if (ln < 16)
      __builtin_nontemporal_store(psum, part_g + ((size_t)(b * 64 + tile)) * DD + dcol);
  }
}

// ---------------- K2: fused q2c reduce + segment 3 ------------------------
// 256 blocks XCD-affine (b = blk&7); each block redundantly reduces its
// batch's 64 tile-partials (64 KB, L2/L3) then writes 128 rows of seg3.
__global__ __launch_bounds__(256) void q2c_seg3_k(
    const float* __restrict__ c,
    const float* __restrict__ pm_g, const float* __restrict__ z_g,
    const float* __restrict__ part_g, float* __restrict__ out)
{
  __shared__ float wk[64];
  int blk = blockIdx.x;
  int b = blk & 7;
  int chunk = blk >> 3;          // 0..31, each 128 rows
  int t = threadIdx.x;

  if (t < 64) {
    float p = pm_g[b * 64 + t];
    float m = p;
    #pragma unroll
    for (int o = 1; o < 64; o <<= 1) m = fmaxf(m, __shfl_xor(m, o));
    float ew = __expf(p - m);
    float zi = ew * z_g[b * 64 + t];
    float s = zi;
    #pragma unroll
    for (int o = 1; o < 64; o <<= 1) s += __shfl_xor(s, o);
    wk[t] = ew / s;
  }
  __syncthreads();

  // per-thread q2c for d = t
  float g = 0.f;
  #pragma unroll 8
  for (int k = 0; k < 64; ++k)
    g += wk[k] * part_g[((size_t)(b * 64 + k)) * DD + t];

  int r0 = chunk * 128;
  for (int r = 0; r < 128; ++r) {
    int row = r0 + r;
    float cv = c[((size_t)(b * CL + row)) * DD + t];
    __builtin_nontemporal_store(cv * g,
        out + ((size_t)(b * CL + row)) * (4 * DD) + 3 * DD + t);
  }
}

extern "C" void kernel_launch(void* const* d_in, const int* in_sizes, int n_in,
                              void* d_out, int out_size, void* d_ws, size_t ws_size,
                              hipStream_t stream) {
  const float* q = (const float*)d_in[0];
  const float* c = (const float*)d_in[1];
  const float* w = (const float*)d_in[2];
  float* out = (float*)d_out;
  char* ws = (char*)d_ws;

  u16*   qbf   = (u16*)(ws);                    // 2,097,152 B
  u16*   qTbf  = (u16*)(ws + 2097152);          // 2,097,152 B
  float* qw    = (float*)(ws + 4194304);        //    16,384 B
  float* pm    = (float*)(ws + 4210688);        //     2,048 B
  float* zb    = (float*)(ws + 4214784);        //     2,048 B
  float* part  = (float*)(ws + 4218880);        //   524,288 B

  prep_q_k<<<512, 256, 0, stream>>>(q, w, qbf, qTbf, qw);
  attn_main_k<<<512, 512, 0, stream>>>(c, w, qbf, qTbf, qw, pm, zb, part, out);
  q2c_seg3_k<<<256, 256, 0, stream>>>(c, pm, zb, part, out);
}

// Round 7
// 94.605 us; speedup vs baseline: 1.7423x; 1.7423x over previous
//
#include <hip/hip_runtime.h>

#define BB 8
#define CL 4096
#define QL 512
#define DD 256

typedef unsigned short u16;
typedef float f32x4 __attribute__((ext_vector_type(4)));
typedef short s16x8 __attribute__((ext_vector_type(8)));

static __device__ __forceinline__ u16 f2bf(float x) {
  unsigned int u = __float_as_uint(x);
  u += 0x7FFFu + ((u >> 16) & 1u);
  return (u16)(u >> 16);
}

// ---------------- K0: prep q (bf16 row-major, bf16 transposed, qw dots) ----
__global__ __launch_bounds__(256) void prep_q_k(
    const float* __restrict__ q, const float* __restrict__ w,
    u16* __restrict__ qbf, u16* __restrict__ qTbf, float* __restrict__ qw_g)
{
  __shared__ u16 qs[8][256];
  __shared__ float red[8][32];
  int blk = blockIdx.x;
  int b = blk & 7;
  int j0 = (blk >> 3) * 8;
  int t = threadIdx.x;
  int r = t >> 5;
  int cs = (t & 31) * 8;

  const float* qrow = q + ((size_t)(b * QL + j0 + r)) * DD + cs;
  float4 v0 = *(const float4*)(qrow);
  float4 v1 = *(const float4*)(qrow + 4);
  float4 w0 = *(const float4*)(w + cs);       // w_q
  float4 w1 = *(const float4*)(w + cs + 4);
  float pw = v0.x*w0.x + v0.y*w0.y + v0.z*w0.z + v0.w*w0.w
           + v1.x*w1.x + v1.y*w1.y + v1.z*w1.z + v1.w*w1.w;

  union { u16 u[8]; uint4 v; } pk;
  pk.u[0]=f2bf(v0.x); pk.u[1]=f2bf(v0.y); pk.u[2]=f2bf(v0.z); pk.u[3]=f2bf(v0.w);
  pk.u[4]=f2bf(v1.x); pk.u[5]=f2bf(v1.y); pk.u[6]=f2bf(v1.z); pk.u[7]=f2bf(v1.w);

  *(uint4*)(qbf + ((size_t)(b * QL + j0 + r)) * DD + cs) = pk.v;
  *(uint4*)(&qs[r][cs]) = pk.v;
  red[r][t & 31] = pw;
  __syncthreads();

  if (t < 8) {
    float s = 0.f;
    #pragma unroll
    for (int k = 0; k < 32; ++k) s += red[t][k];
    qw_g[b * QL + j0 + t] = s;
  }

  int d = t;
  union { u16 u[8]; uint4 v; } tp;
  #pragma unroll
  for (int jj = 0; jj < 8; ++jj) tp.u[jj] = qs[jj][d];
  *(uint4*)(qTbf + ((size_t)(b * DD + d)) * QL + j0) = tp.v;
}

// ---------------- K1: 64-row c tile, 8 waves, 2 blocks/CU -----------------
// GEMM2 uses SWAPPED operands: mfma(qT_frag, P_frag) so each lane's f32x4
// holds 4 consecutive d of one c-row -> float4 epilogue stores/loads.
__global__ __launch_bounds__(512, 4) void attn_main_k(
    const float* __restrict__ c, const float* __restrict__ w,
    const u16* __restrict__ qbf, const u16* __restrict__ qTbf,
    const float* __restrict__ qw_g,
    float* __restrict__ pm_g, float* __restrict__ z_g,
    float* __restrict__ part_g, float* __restrict__ out)
{
  __shared__ u16 pool[64 * 512];     // cm: [r*256+(d^swz)] (32KB); P: [r*512+(j^swz)] (64KB)
  __shared__ float qw_s[QL];
  __shared__ float cw_s[64];
  __shared__ float red_m[64][8];     // [row][wave]
  __shared__ float red_z[64][8];
  __shared__ float invz_s[64];
  __shared__ float wgt_s[64];

  int t = threadIdx.x;
  int blk = blockIdx.x;
  int b = blk & 7;
  int tile = blk >> 3;
  int it0 = tile * 64;

  // ---- staging: c tile -> cm bf16 LDS (swizzled), cw dots, seg0 copy ----
  {
    int r = t >> 3;
    int cg = (t & 7) * 32;
    int swz = (r & 7) << 3;
    const float* crow = c + ((size_t)(b * CL + it0 + r)) * DD + cg;
    float* outrow = out + ((size_t)(b * CL + it0 + r)) * (4 * DD) + cg;
    float pcw = 0.f;
    #pragma unroll
    for (int u = 0; u < 32; u += 4) {
      f32x4 cv  = *(const f32x4*)(crow + u);
      f32x4 wcv = *(const f32x4*)(w + DD + cg + u);      // w_c
      f32x4 wmv = *(const f32x4*)(w + 2 * DD + cg + u);  // w_m
      *(f32x4*)(outrow + u) = cv;                        // segment 0
      pcw += cv[0]*wcv[0] + cv[1]*wcv[1] + cv[2]*wcv[2] + cv[3]*wcv[3];
      ushort4 hv;
      hv.x = f2bf(cv[0] * wmv[0]); hv.y = f2bf(cv[1] * wmv[1]);
      hv.z = f2bf(cv[2] * wmv[2]); hv.w = f2bf(cv[3] * wmv[3]);
      *(ushort4*)(&pool[r * 256 + ((cg + u) ^ swz)]) = hv;
    }
    pcw += __shfl_xor(pcw, 1);
    pcw += __shfl_xor(pcw, 2);
    pcw += __shfl_xor(pcw, 4);
    if ((t & 7) == 0) cw_s[r] = pcw;
    qw_s[t] = qw_g[b * QL + t];
  }
  __syncthreads();

  int wv = t >> 6;       // wave 0..7
  int ln = t & 63;
  int lr = ln & 15;
  int lg = ln >> 4;
  int jc = wv * 64;      // GEMM1 j-chunk
  int aswz = (lr & 7) << 3;

  // ---- GEMM1: S chunk = cm(64x256) @ q^T; B frags from L2, k+1 prefetch --
  f32x4 acc[4][4];
  #pragma unroll
  for (int m = 0; m < 4; ++m)
    #pragma unroll
    for (int n = 0; n < 4; ++n) acc[m][n] = (f32x4){0.f, 0.f, 0.f, 0.f};

  const u16* qb = qbf + (size_t)b * QL * DD + (size_t)(jc + lr) * DD + lg * 8;
  s16x8 bqn[4];
  #pragma unroll
  for (int n = 0; n < 4; ++n) bqn[n] = *(const s16x8*)(qb + (size_t)(n * 16) * DD);
  #pragma unroll
  for (int kk = 0; kk < 8; ++kk) {
    s16x8 bqc[4];
    #pragma unroll
    for (int n = 0; n < 4; ++n) bqc[n] = bqn[n];
    if (kk < 7) {
      #pragma unroll
      for (int n = 0; n < 4; ++n)
        bqn[n] = *(const s16x8*)(qb + (size_t)(n * 16) * DD + (kk + 1) * 32);
    }
    s16x8 a[4];
    #pragma unroll
    for (int m = 0; m < 4; ++m)
      a[m] = *(const s16x8*)(&pool[(m * 16 + lr) * 256 + ((kk * 32 + lg * 8) ^ aswz)]);
    #pragma unroll
    for (int m = 0; m < 4; ++m)
      #pragma unroll
      for (int n = 0; n < 4; ++n)
        acc[m][n] = __builtin_amdgcn_mfma_f32_16x16x32_bf16(a[m], bqc[n], acc[m][n], 0, 0, 0);
  }

  // ---- softmax pass 1: bias + row max (D: col=lr->j, row=lg*4+rr->i) ----
  float qwv[4];
  #pragma unroll
  for (int n = 0; n < 4; ++n) qwv[n] = qw_s[jc + n * 16 + lr];

  #pragma unroll
  for (int m = 0; m < 4; ++m) {
    #pragma unroll
    for (int rr = 0; rr < 4; ++rr) {
      int row = m * 16 + lg * 4 + rr;
      float cwv = cw_s[row];
      float mx = -1e30f;
      #pragma unroll
      for (int n = 0; n < 4; ++n) {
        float s = acc[m][n][rr] + cwv + qwv[n];
        acc[m][n][rr] = s;
        mx = fmaxf(mx, s);
      }
      mx = fmaxf(mx, __shfl_xor(mx, 1));
      mx = fmaxf(mx, __shfl_xor(mx, 2));
      mx = fmaxf(mx, __shfl_xor(mx, 4));
      mx = fmaxf(mx, __shfl_xor(mx, 8));
      if (lr == 0) red_m[row][wv] = mx;
    }
  }
  __syncthreads();   // red_m visible; cm reads done -> pool reusable as P

  // ---- softmax pass 2: exp, write raw-exp P (swizzled), z partials ----
  #pragma unroll
  for (int m = 0; m < 4; ++m) {
    #pragma unroll
    for (int rr = 0; rr < 4; ++rr) {
      int row = m * 16 + lg * 4 + rr;
      float4 m0 = *(const float4*)(&red_m[row][0]);
      float4 m1 = *(const float4*)(&red_m[row][4]);
      float mr = fmaxf(fmaxf(fmaxf(m0.x, m0.y), fmaxf(m0.z, m0.w)),
                       fmaxf(fmaxf(m1.x, m1.y), fmaxf(m1.z, m1.w)));
      int pswz = (row & 7) << 3;
      float s = 0.f;
      #pragma unroll
      for (int n = 0; n < 4; ++n) {
        float e = __expf(acc[m][n][rr] - mr);
        pool[row * 512 + ((jc + n * 16 + lr) ^ pswz)] = f2bf(e);
        s += e;
      }
      s += __shfl_xor(s, 1);
      s += __shfl_xor(s, 2);
      s += __shfl_xor(s, 4);
      s += __shfl_xor(s, 8);
      if (lr == 0) red_z[row][wv] = s;
    }
  }
  __syncthreads();   // P + red_z visible

  // ---- wave 0: per-row invz/wgt into LDS; pm/z stats to global ----
  if (wv == 0) {
    int row = ln;  // 64 lanes -> 64 rows
    float4 m0 = *(const float4*)(&red_m[row][0]);
    float4 m1 = *(const float4*)(&red_m[row][4]);
    float mr = fmaxf(fmaxf(fmaxf(m0.x, m0.y), fmaxf(m0.z, m0.w)),
                     fmaxf(fmaxf(m1.x, m1.y), fmaxf(m1.z, m1.w)));
    float4 z0 = *(const float4*)(&red_z[row][0]);
    float4 z1 = *(const float4*)(&red_z[row][4]);
    float z = z0.x + z0.y + z0.z + z0.w + z1.x + z1.y + z1.z + z1.w;
    invz_s[row] = 1.0f / z;
    float pmx = mr;
    #pragma unroll
    for (int o = 1; o < 64; o <<= 1) pmx = fmaxf(pmx, __shfl_xor(pmx, o));
    float wg = __expf(mr - pmx);
    wgt_s[row] = wg;
    float zs = wg;
    #pragma unroll
    for (int o = 1; o < 64; o <<= 1) zs += __shfl_xor(zs, o);
    if (ln == 0) { pm_g[b * 64 + tile] = pmx; z_g[b * 64 + tile] = zs; }
  }

  // ---- GEMM2 (swapped): c2q^T frag = qT(32x512) x P(64x512) ----
  // o2[m][n]: lane holds c2q[i = m*16+lr][d = dc+n*16+lg*4 .. +3]
  f32x4 o2[4][2];
  #pragma unroll
  for (int m = 0; m < 4; ++m)
    #pragma unroll
    for (int n = 0; n < 2; ++n) o2[m][n] = (f32x4){0.f, 0.f, 0.f, 0.f};

  int dc = wv * 32;
  const u16* qtb = qTbf + (size_t)b * DD * QL + (size_t)(dc + lr) * QL + lg * 8;
  s16x8 bvn[2];
  #pragma unroll
  for (int n = 0; n < 2; ++n) bvn[n] = *(const s16x8*)(qtb + (size_t)(n * 16) * QL);
  #pragma unroll 4
  for (int kk = 0; kk < 16; ++kk) {
    s16x8 bvc[2];
    #pragma unroll
    for (int n = 0; n < 2; ++n) bvc[n] = bvn[n];
    if (kk < 15) {
      #pragma unroll
      for (int n = 0; n < 2; ++n)
        bvn[n] = *(const s16x8*)(qtb + (size_t)(n * 16) * QL + (kk + 1) * 32);
    }
    s16x8 pa[4];
    #pragma unroll
    for (int m = 0; m < 4; ++m)
      pa[m] = *(const s16x8*)(&pool[(m * 16 + lr) * 512 + ((kk * 32 + lg * 8) ^ aswz)]);
    #pragma unroll
    for (int m = 0; m < 4; ++m)
      #pragma unroll
      for (int n = 0; n < 2; ++n)
        o2[m][n] = __builtin_amdgcn_mfma_f32_16x16x32_bf16(bvc[n], pa[m], o2[m][n], 0, 0, 0);
  }
  __syncthreads();   // invz_s/wgt_s visible

  // ---- epilogue: float4 seg1 (c2q), seg2 (c*c2q), q2c partial ----
  f32x4 psum[2];
  psum[0] = (f32x4){0.f, 0.f, 0.f, 0.f};
  psum[1] = (f32x4){0.f, 0.f, 0.f, 0.f};
  const float* cb = c + ((size_t)(b * CL + it0)) * DD;
  float* ob = out + ((size_t)(b * CL + it0)) * (4 * DD);
  #pragma unroll
  for (int n = 0; n < 2; ++n) {
    int d4 = dc + n * 16 + lg * 4;
    #pragma unroll
    for (int m = 0; m < 4; ++m) {
      int i = m * 16 + lr;
      f32x4 cv = *(const f32x4*)(cb + (size_t)i * DD + d4);
      f32x4 c2q = o2[m][n] * invz_s[i];
      *(f32x4*)(ob + (size_t)i * (4 * DD) + DD + d4) = c2q;
      *(f32x4*)(ob + (size_t)i * (4 * DD) + 2 * DD + d4) = cv * c2q;
      psum[n] += wgt_s[i] * cv;
    }
    #pragma unroll
    for (int j = 0; j < 4; ++j) {
      psum[n][j] += __shfl_xor(psum[n][j], 1);
      psum[n][j] += __shfl_xor(psum[n][j], 2);
      psum[n][j] += __shfl_xor(psum[n][j], 4);
      psum[n][j] += __shfl_xor(psum[n][j], 8);
    }
    if (lr == 0)
      *(f32x4*)(part_g + ((size_t)(b * 64 + tile)) * DD + d4) = psum[n];
  }
}

// ---------------- K2: fused q2c reduce + segment 3 (float4) ---------------
__global__ __launch_bounds__(256) void q2c_seg3_k(
    const float* __restrict__ c,
    const float* __restrict__ pm_g, const float* __restrict__ z_g,
    const float* __restrict__ part_g, float* __restrict__ out)
{
  __shared__ float wk[64];
  int blk = blockIdx.x;
  int b = blk & 7;
  int chunk = blk >> 3;          // 0..31, each 128 rows
  int t = threadIdx.x;

  if (t < 64) {
    float p = pm_g[b * 64 + t];
    float m = p;
    #pragma unroll
    for (int o = 1; o < 64; o <<= 1) m = fmaxf(m, __shfl_xor(m, o));
    float ew = __expf(p - m);
    float zi = ew * z_g[b * 64 + t];
    float s = zi;
    #pragma unroll
    for (int o = 1; o < 64; o <<= 1) s += __shfl_xor(s, o);
    wk[t] = ew / s;
  }
  __syncthreads();

  // thread t: col quad c4 = (t&63)*4 (4 threads redundant per quad)
  int c4 = (t & 63) * 4;
  f32x4 g = (f32x4){0.f, 0.f, 0.f, 0.f};
  #pragma unroll 8
  for (int k = 0; k < 64; ++k)
    g += wk[k] * *(const f32x4*)(part_g + ((size_t)(b * 64 + k)) * DD + c4);

  int r0 = chunk * 128 + (t >> 6);
  for (int it = 0; it < 32; ++it) {
    int row = r0 + it * 4;
    f32x4 cv = *(const f32x4*)(c + ((size_t)(b * CL + row)) * DD + c4);
    *(f32x4*)(out + ((size_t)(b * CL + row)) * (4 * DD) + 3 * DD + c4) = cv * g;
  }
}

extern "C" void kernel_launch(void* const* d_in, const int* in_sizes, int n_in,
                              void* d_out, int out_size, void* d_ws, size_t ws_size,
                              hipStream_t stream) {
  const float* q = (const float*)d_in[0];
  const float* c = (const float*)d_in[1];
  const float* w = (const float*)d_in[2];
  float* out = (float*)d_out;
  char* ws = (char*)d_ws;

  u16*   qbf   = (u16*)(ws);                    // 2,097,152 B
  u16*   qTbf  = (u16*)(ws + 2097152);          // 2,097,152 B
  float* qw    = (float*)(ws + 4194304);        //    16,384 B
  float* pm    = (float*)(ws + 4210688);        //     2,048 B
  float* zb    = (float*)(ws + 4214784);        //     2,048 B
  float* part  = (float*)(ws + 4218880);        //   524,288 B

  prep_q_k<<<512, 256, 0, stream>>>(q, w, qbf, qTbf, qw);
  attn_main_k<<<512, 512, 0, stream>>>(c, w, qbf, qTbf, qw, pm, zb, part, out);
  q2c_seg3_k<<<256, 256, 0, stream>>>(c, pm, zb, part, out);
}